// Round 5
// baseline (372.066 us; speedup 1.0000x reference)
//
#include <hip/hip_runtime.h>
#include <hip/hip_bf16.h>
#include <stdint.h>

// ---------- helpers ----------
__device__ __forceinline__ unsigned short f2bf(float f) {
    __hip_bfloat16 h = __float2bfloat16(f);   // RNE, matches JAX astype
    return *reinterpret_cast<unsigned short*>(&h);
}
__device__ __forceinline__ float bf2f(unsigned short u) {
    __hip_bfloat16 h = *reinterpret_cast<__hip_bfloat16*>(&u);
    return __bfloat162float(h);
}

typedef __attribute__((ext_vector_type(8))) short bf16x8;
typedef __attribute__((ext_vector_type(4))) float f32x4;

__device__ __forceinline__ void async16(const void* g, void* l) {
    __builtin_amdgcn_global_load_lds(
        (const __attribute__((address_space(1))) unsigned int*)g,
        (__attribute__((address_space(3))) unsigned int*)l,
        16, 0, 0);
}

// ---------- kernel 1: ternary-quantize weight (replicates JAX bf16 per-op rounding) ----------
__global__ __launch_bounds__(256) void quant_kernel(const float* __restrict__ W,
                                                    unsigned short* __restrict__ Wq) {
    int idx = blockIdx.x * 256 + threadIdx.x;
    float wf = W[idx];
    float wbf = bf2f(f2bf(wf));            // w = weight.astype(bf16)
    float a = fabsf(wbf);
    float s = a;
    #pragma unroll
    for (int off = 32; off; off >>= 1) s += __shfl_xor(s, off, 64);
    float mean = s * (1.0f / 64.0f);       // f32 accumulation (JAX upcasts bf16 mean)
    float sf = bf2f(f2bf(mean));           // cast result back to bf16
    sf = fmaxf(sf, 1.0011718e-08f);        // clip(scale, 1e-8) in bf16 domain
    float quot = bf2f(f2bf(wbf / sf));     // bf16 division = f32 div then bf16 round
    float q = rintf(quot);                 // round half-to-even
    q = fminf(1.0f, fmaxf(-1.0f, q));
    float qs = q * sf;                     // exact bf16 value (q in {-1,0,1})
    float d  = bf2f(f2bf(qs - wbf));       // bf16 subtraction rounding
    Wq[idx] = f2bf(wbf + d);               // bf16 add rounding -> forward weight
}

// ---------- kernel 2: RMS-norm rows of 4096, write bf16 ----------
__global__ __launch_bounds__(256) void norm_kernel(const float* __restrict__ X,
                                                   unsigned short* __restrict__ Xb) {
    __shared__ float red[4];
    const long long row = blockIdx.x;
    const float4* xr = (const float4*)(X + row * 4096);
    const int t = threadIdx.x;
    float4 v[4];
    float ss = 0.f;
    #pragma unroll
    for (int i = 0; i < 4; ++i) {
        v[i] = xr[i * 256 + t];
        ss += v[i].x * v[i].x + v[i].y * v[i].y + v[i].z * v[i].z + v[i].w * v[i].w;
    }
    #pragma unroll
    for (int off = 32; off; off >>= 1) ss += __shfl_xor(ss, off, 64);
    if ((t & 63) == 0) red[t >> 6] = ss;
    __syncthreads();
    const float tot = red[0] + red[1] + red[2] + red[3];
    const float scale = 1.0f / sqrtf(tot * (1.0f / 4096.0f) + 1.1920928955078125e-07f);
    ushort4* ob = (ushort4*)(Xb + row * 4096);
    #pragma unroll
    for (int i = 0; i < 4; ++i) {
        ushort4 o;
        o.x = f2bf(v[i].x * scale);
        o.y = f2bf(v[i].y * scale);
        o.z = f2bf(v[i].z * scale);
        o.w = f2bf(v[i].w * scale);
        ob[i * 256 + t] = o;
    }
}

// ---------- kernel 3: grouped GEMM, 256x256 tile, BK=64, 8-phase schedule ----------
// Xb: [8192][4096] bf16, Wq: [4096][1024] bf16 (B^T), Out: [8192][4096] fp32.
// 8 waves (2M x 4N), per-wave 128x64 output. 16 K-tiles of 64; 8 iterations.
// LDS 128 KiB: 2 dbuf x (A[256][64] + B[256][64]).
// XCD pairing: per XCD, consecutive blocks = same M, two N-blocks -> A L2-shared.
// Epilogue: wave-private LDS transpose (stride 68 f32) -> dwordx4 stores.
__global__ __launch_bounds__(512, 2) void gemm_kernel(const unsigned short* __restrict__ Xb,
                                                      const unsigned short* __restrict__ Wq,
                                                      float* __restrict__ Out) {
    __shared__ __attribute__((aligned(16))) unsigned short ls[65536];   // 128 KiB

    const int tid = threadIdx.x;
    const int lane = tid & 63;
    const int laneR = lane & 15;
    const int wv = tid >> 6;
    const int wr = wv >> 2;           // 0..1
    const int wc = wv & 3;            // 0..3

    // T1: XCD pairing map (bijective, 512 % 8 == 0):
    // xcd = bid&7 owns N-supercols {2*xcd, 2*xcd+1}; consecutive local blocks
    // alternate N so both readers of an A-panel are concurrent on one XCD.
    const int bid = blockIdx.x;
    const int bm0 = (bid >> 4) * 256;                       // m = bid>>4 in [0,32)
    const int bn0 = ((bid & 7) * 2 + ((bid >> 3) & 1)) * 256;   // n in [0,16)
    const int g = bn0 >> 10;

    // staging: thread covers row srow (+64/+128/+192 via half/j), colblock (tid&7) pre-swizzled
    const int srow = tid >> 3;                              // 0..63
    const int cswz8 = (((tid & 7) ^ (srow & 7)) << 3);      // element offset in row
    const unsigned short* aG = Xb + (long long)(bm0 + srow) * 4096 + g * 1024 + cswz8;
    const unsigned short* bG = Wq + (long long)(bn0 + srow) * 1024 + cswz8;

    // read-side swizzle: kb = ks*4 + (lane>>4), slot = kb ^ (row&7), row&7 == lane&7
    const int col0 = (((lane >> 4) ^ (lane & 7)) << 3);
    const int col1 = col0 ^ 32;

    // LDS region bases (elements): buf0 A, buf0 B, buf1 A, buf1 B
    enum { A0 = 0, B0 = 16384, A1 = 32768, B1 = 49152 };

    const int aRow = (wr * 128 + laneR) * 64;   // + 4096 for high half, + mi*1024
    const int bRow = (wc * 64 + laneR) * 64;    // + ni*1024

#define STAGE_A(base, kt, h) do { \
    async16(aG + ((long long)((h) * 128) * 4096 + (kt) * 64),      ls + (base) + (h) * 8192 + tid * 8); \
    async16(aG + ((long long)((h) * 128 + 64) * 4096 + (kt) * 64), ls + (base) + (h) * 8192 + 4096 + tid * 8); \
} while (0)
#define STAGE_B(base, kt, h) do { \
    async16(bG + ((long long)((h) * 128) * 1024 + (kt) * 64),      ls + (base) + (h) * 8192 + tid * 8); \
    async16(bG + ((long long)((h) * 128 + 64) * 1024 + (kt) * 64), ls + (base) + (h) * 8192 + 4096 + tid * 8); \
} while (0)
#define LD(off) (*(const bf16x8*)(ls + (off)))
// one MFMA acc-row (4 MFMA): acc[AI][NB..NB+1] += F (x2 k-halves) * BB
#define MROW(AI, NB, FF, BB) do { \
    _Pragma("unroll") \
    for (int ni = 0; ni < 2; ++ni) { \
        acc[AI][(NB) + ni] = __builtin_amdgcn_mfma_f32_16x16x32_bf16((FF)[0], (BB)[ni][0], acc[AI][(NB) + ni], 0, 0, 0); \
        acc[AI][(NB) + ni] = __builtin_amdgcn_mfma_f32_16x16x32_bf16((FF)[1], (BB)[ni][1], acc[AI][(NB) + ni], 0, 0, 0); \
    } \
} while (0)
#define BAR() __builtin_amdgcn_s_barrier()
#define PRIO1() __builtin_amdgcn_s_setprio(1)
#define PRIO0() __builtin_amdgcn_s_setprio(0)

    f32x4 acc[8][4];
    #pragma unroll
    for (int i = 0; i < 8; ++i)
        #pragma unroll
        for (int j = 0; j < 4; ++j) acc[i][j] = (f32x4){0.f, 0.f, 0.f, 0.f};

    bf16x8 a[4][2], ah2[2][2], b[2][2], c[2][2];

    // ---- prologue: kt0 full into buf0 (8 loads), B(kt1) into buf1 (4 loads)
    STAGE_A(A0, 0, 0); STAGE_A(A0, 0, 1);
    STAGE_B(B0, 0, 0); STAGE_B(B0, 0, 1);
    STAGE_B(B1, 1, 0); STAGE_B(B1, 1, 1);
    asm volatile("s_waitcnt vmcnt(4)" ::: "memory");   // kt0 resident; B(kt1) in flight
    BAR();

    #pragma unroll 1
    for (int it = 0; it < 8; ++it) {
        const int kt1 = it * 2 + 1;
        const bool pf = (it < 7);

        // ---- P1: reads b01 + aLow (buf0); stage A_h0(kt1)->buf1; MFMA Q(0,0) ----
        #pragma unroll
        for (int ni = 0; ni < 2; ++ni) { b[ni][0] = LD(B0 + bRow + ni * 1024 + col0); b[ni][1] = LD(B0 + bRow + ni * 1024 + col1); }
        #pragma unroll
        for (int mi = 0; mi < 4; ++mi) { a[mi][0] = LD(A0 + aRow + mi * 1024 + col0); a[mi][1] = LD(A0 + aRow + mi * 1024 + col1); }
        STAGE_A(A1, kt1, 0);
        BAR(); PRIO1();
        MROW(0, 0, a[0], b); MROW(1, 0, a[1], b); MROW(2, 0, a[2], b); MROW(3, 0, a[3], b);
        PRIO0(); BAR();

        // ---- P2: reads b23 + aHigh01 (buf0); stage A_h1(kt1)->buf1; MFMA Q(0,1) ----
        #pragma unroll
        for (int ni = 0; ni < 2; ++ni) { c[ni][0] = LD(B0 + bRow + (ni + 2) * 1024 + col0); c[ni][1] = LD(B0 + bRow + (ni + 2) * 1024 + col1); }
        #pragma unroll
        for (int j = 0; j < 2; ++j) { ah2[j][0] = LD(A0 + aRow + 4096 + j * 1024 + col0); ah2[j][1] = LD(A0 + aRow + 4096 + j * 1024 + col1); }
        STAGE_A(A1, kt1, 1);
        BAR(); PRIO1();
        MROW(0, 2, a[0], c); MROW(1, 2, a[1], c); MROW(2, 2, a[2], c); MROW(3, 2, a[3], c);
        PRIO0(); BAR();

        // ---- P3: reads aHigh23 (buf0, into dead aLow regs); stage B_h0(kt+2); MFMA Q(1,0) ----
        #pragma unroll
        for (int j = 0; j < 2; ++j) { a[j][0] = LD(A0 + aRow + 4096 + (j + 2) * 1024 + col0); a[j][1] = LD(A0 + aRow + 4096 + (j + 2) * 1024 + col1); }
        if (pf) STAGE_B(B0, kt1 + 1, 0);
        BAR(); PRIO1();
        MROW(4, 0, ah2[0], b); MROW(5, 0, ah2[1], b); MROW(6, 0, a[0], b); MROW(7, 0, a[1], b);
        PRIO0(); BAR();

        // ---- P4: stage B_h1(kt+2); MFMA Q(1,1); counted vmcnt ----
        if (pf) STAGE_B(B0, kt1 + 1, 1);
        BAR(); PRIO1();
        MROW(4, 2, ah2[0], c); MROW(5, 2, ah2[1], c); MROW(6, 2, a[0], c); MROW(7, 2, a[1], c);
        PRIO0();
        if (pf) { asm volatile("s_waitcnt vmcnt(4)" ::: "memory"); }
        else    { asm volatile("s_waitcnt vmcnt(0)" ::: "memory"); }
        BAR();

        // ---- P5: reads b01 + aLow (buf1); stage A_h0(kt+2)->buf0; MFMA Q(0,0) ----
        #pragma unroll
        for (int ni = 0; ni < 2; ++ni) { b[ni][0] = LD(B1 + bRow + ni * 1024 + col0); b[ni][1] = LD(B1 + bRow + ni * 1024 + col1); }
        #pragma unroll
        for (int mi = 0; mi < 4; ++mi) { a[mi][0] = LD(A1 + aRow + mi * 1024 + col0); a[mi][1] = LD(A1 + aRow + mi * 1024 + col1); }
        if (pf) STAGE_A(A0, kt1 + 1, 0);
        BAR(); PRIO1();
        MROW(0, 0, a[0], b); MROW(1, 0, a[1], b); MROW(2, 0, a[2], b); MROW(3, 0, a[3], b);
        PRIO0(); BAR();

        // ---- P6: reads b23 + aHigh01 (buf1); stage A_h1(kt+2)->buf0; MFMA Q(0,1) ----
        #pragma unroll
        for (int ni = 0; ni < 2; ++ni) { c[ni][0] = LD(B1 + bRow + (ni + 2) * 1024 + col0); c[ni][1] = LD(B1 + bRow + (ni + 2) * 1024 + col1); }
        #pragma unroll
        for (int j = 0; j < 2; ++j) { ah2[j][0] = LD(A1 + aRow + 4096 + j * 1024 + col0); ah2[j][1] = LD(A1 + aRow + 4096 + j * 1024 + col1); }
        if (pf) STAGE_A(A0, kt1 + 1, 1);
        BAR(); PRIO1();
        MROW(0, 2, a[0], c); MROW(1, 2, a[1], c); MROW(2, 2, a[2], c); MROW(3, 2, a[3], c);
        PRIO0(); BAR();

        // ---- P7: reads aHigh23 (buf1); stage B_h0(kt1+2)->buf1; MFMA Q(1,0) ----
        #pragma unroll
        for (int j = 0; j < 2; ++j) { a[j][0] = LD(A1 + aRow + 4096 + (j + 2) * 1024 + col0); a[j][1] = LD(A1 + aRow + 4096 + (j + 2) * 1024 + col1); }
        if (pf) STAGE_B(B1, kt1 + 2, 0);
        BAR(); PRIO1();
        MROW(4, 0, ah2[0], b); MROW(5, 0, ah2[1], b); MROW(6, 0, a[0], b); MROW(7, 0, a[1], b);
        PRIO0(); BAR();

        // ---- P8: stage B_h1(kt1+2); MFMA Q(1,1); counted vmcnt ----
        if (pf) STAGE_B(B1, kt1 + 2, 1);
        BAR(); PRIO1();
        MROW(4, 2, ah2[0], c); MROW(5, 2, ah2[1], c); MROW(6, 2, a[0], c); MROW(7, 2, a[1], c);
        PRIO0();
        if (pf) { asm volatile("s_waitcnt vmcnt(4)" ::: "memory"); }
        BAR();
    }

    // ---- epilogue: wave-private LDS transpose -> coalesced dwordx4 stores ----
    // After final BAR all LDS is dead. Per wave: 16x68 f32 region (4352 B).
    // Write side: acc[mi][ni][r] -> lds[row=(lane>>4)*4+r][col=ni*16+laneR];
    //   banks = exactly 2 lanes/bank (free, m136).
    // Read side: row = j*4 + (lane>>4), 16 lanes cover 64 contiguous cols ->
    //   f32x4 aligned (68*4=272 B row stride, 16B-aligned), balanced 8/bank.
    // Store: 16 lanes x 16B = 256 B contiguous per row segment.
    {
        float* lf = (float*)ls;
        const int base = wv * 1088;               // 16 * 68 floats per wave
        const int wrow0 = (lane >> 4) * 4;
        const int rrow = lane >> 4;
        const int rcol = laneR * 4;
        #pragma unroll 1
        for (int mi = 0; mi < 8; ++mi) {
            #pragma unroll
            for (int ni = 0; ni < 4; ++ni)
                #pragma unroll
                for (int r = 0; r < 4; ++r)
                    lf[base + (wrow0 + r) * 68 + ni * 16 + laneR] = acc[mi][ni][r];
            // compiler inserts lgkmcnt(0) between aliasing ds_write/ds_read
            #pragma unroll
            for (int j = 0; j < 4; ++j) {
                f32x4 v = *(const f32x4*)&lf[base + (j * 4 + rrow) * 68 + rcol];
                const long long rg = (long long)(bm0 + wr * 128 + mi * 16 + j * 4 + rrow);
                *(f32x4*)&Out[rg * 4096 + bn0 + wc * 64 + rcol] = v;
            }
        }
    }
#undef STAGE_A
#undef STAGE_B
#undef LD
#undef MROW
#undef BAR
#undef PRIO1
#undef PRIO0
}

// ---------- launcher ----------
extern "C" void kernel_launch(void* const* d_in, const int* in_sizes, int n_in,
                              void* d_out, int out_size, void* d_ws, size_t ws_size,
                              hipStream_t stream) {
    const float* x = (const float*)d_in[0];     // (2,4096,4096) fp32
    const float* w = (const float*)d_in[1];     // (4096,1024) fp32
    float* out = (float*)d_out;                 // (2,4096,4096) fp32

    unsigned short* xb = (unsigned short*)d_ws;                   // 8192*4096 bf16 = 64 MiB
    unsigned short* wq = xb + (size_t)8192 * 4096;                // 4096*1024 bf16 = 8 MiB

    quant_kernel<<<4096 * 1024 / 256, 256, 0, stream>>>(w, wq);
    norm_kernel<<<8192, 256, 0, stream>>>(x, xb);
    gemm_kernel<<<512, 512, 0, stream>>>(xb, wq, out);
}

// Round 6
// 315.801 us; speedup vs baseline: 1.1782x; 1.1782x over previous
//
#include <hip/hip_runtime.h>
#include <hip/hip_bf16.h>
#include <stdint.h>

// ---------- helpers ----------
__device__ __forceinline__ unsigned short f2bf(float f) {
    __hip_bfloat16 h = __float2bfloat16(f);   // RNE, matches JAX astype
    return *reinterpret_cast<unsigned short*>(&h);
}
__device__ __forceinline__ float bf2f(unsigned short u) {
    __hip_bfloat16 h = *reinterpret_cast<__hip_bfloat16*>(&u);
    return __bfloat162float(h);
}

typedef __attribute__((ext_vector_type(8))) short bf16x8;
typedef __attribute__((ext_vector_type(4))) float f32x4;

__device__ __forceinline__ void async16(const void* g, void* l) {
    __builtin_amdgcn_global_load_lds(
        (const __attribute__((address_space(1))) unsigned int*)g,
        (__attribute__((address_space(3))) unsigned int*)l,
        16, 0, 0);
}

// ---------- kernel 1: ternary-quantize weight (replicates JAX bf16 per-op rounding) ----------
__global__ __launch_bounds__(256) void quant_kernel(const float* __restrict__ W,
                                                    unsigned short* __restrict__ Wq) {
    int idx = blockIdx.x * 256 + threadIdx.x;
    float wf = W[idx];
    float wbf = bf2f(f2bf(wf));            // w = weight.astype(bf16)
    float a = fabsf(wbf);
    float s = a;
    #pragma unroll
    for (int off = 32; off; off >>= 1) s += __shfl_xor(s, off, 64);
    float mean = s * (1.0f / 64.0f);       // f32 accumulation (JAX upcasts bf16 mean)
    float sf = bf2f(f2bf(mean));           // cast result back to bf16
    sf = fmaxf(sf, 1.0011718e-08f);        // clip(scale, 1e-8) in bf16 domain
    float quot = bf2f(f2bf(wbf / sf));     // bf16 division = f32 div then bf16 round
    float q = rintf(quot);                 // round half-to-even
    q = fminf(1.0f, fmaxf(-1.0f, q));
    float qs = q * sf;                     // exact bf16 value (q in {-1,0,1})
    float d  = bf2f(f2bf(qs - wbf));       // bf16 subtraction rounding
    Wq[idx] = f2bf(wbf + d);               // bf16 add rounding -> forward weight
}

// ---------- kernel 2: RMS-norm rows of 4096, write bf16 ----------
__global__ __launch_bounds__(256) void norm_kernel(const float* __restrict__ X,
                                                   unsigned short* __restrict__ Xb) {
    __shared__ float red[4];
    const long long row = blockIdx.x;
    const float4* xr = (const float4*)(X + row * 4096);
    const int t = threadIdx.x;
    float4 v[4];
    float ss = 0.f;
    #pragma unroll
    for (int i = 0; i < 4; ++i) {
        v[i] = xr[i * 256 + t];
        ss += v[i].x * v[i].x + v[i].y * v[i].y + v[i].z * v[i].z + v[i].w * v[i].w;
    }
    #pragma unroll
    for (int off = 32; off; off >>= 1) ss += __shfl_xor(ss, off, 64);
    if ((t & 63) == 0) red[t >> 6] = ss;
    __syncthreads();
    const float tot = red[0] + red[1] + red[2] + red[3];
    const float scale = 1.0f / sqrtf(tot * (1.0f / 4096.0f) + 1.1920928955078125e-07f);
    ushort4* ob = (ushort4*)(Xb + row * 4096);
    #pragma unroll
    for (int i = 0; i < 4; ++i) {
        ushort4 o;
        o.x = f2bf(v[i].x * scale);
        o.y = f2bf(v[i].y * scale);
        o.z = f2bf(v[i].z * scale);
        o.w = f2bf(v[i].w * scale);
        ob[i * 256 + t] = o;
    }
}

// ---------- kernel 3: grouped GEMM, 256x256 tile, BK=64, 8-phase schedule ----------
// Xb: [8192][4096] bf16, Wq: [4096][1024] bf16 (B^T), Out: [8192][4096] fp32.
// 8 waves (2M x 4N), per-wave 128x64 output. 16 K-tiles of 64; 8 iterations.
// LDS 128 KiB: 2 dbuf x (A[256][64] + B[256][64]).
// XCD pairing: per XCD, consecutive blocks = same M, two N-blocks -> A L2-shared.
// SWAPPED-OPERAND MFMA: mfma(b_frag, a_frag, acc) -> D: lane&15 = m,
// (lane>>4)*4+r = n  => each acc[mi][ni] is a contiguous f32x4 in Out.
// Epilogue: direct cached global f32x4 stores from accumulators.
__global__ __launch_bounds__(512, 2) void gemm_kernel(const unsigned short* __restrict__ Xb,
                                                      const unsigned short* __restrict__ Wq,
                                                      float* __restrict__ Out) {
    __shared__ __attribute__((aligned(16))) unsigned short ls[65536];   // 128 KiB

    const int tid = threadIdx.x;
    const int lane = tid & 63;
    const int laneR = lane & 15;
    const int wv = tid >> 6;
    const int wr = wv >> 2;           // 0..1
    const int wc = wv & 3;            // 0..3

    // T1: XCD pairing map (bijective, 512 % 8 == 0):
    // xcd = bid&7 owns N-supercols {2*xcd, 2*xcd+1}; consecutive local blocks
    // alternate N so both readers of an A-panel are concurrent on one XCD.
    const int bid = blockIdx.x;
    const int bm0 = (bid >> 4) * 256;                       // m = bid>>4 in [0,32)
    const int bn0 = ((bid & 7) * 2 + ((bid >> 3) & 1)) * 256;   // n in [0,16)
    const int g = bn0 >> 10;

    // staging: thread covers row srow (+64/+128/+192 via half/j), colblock (tid&7) pre-swizzled
    const int srow = tid >> 3;                              // 0..63
    const int cswz8 = (((tid & 7) ^ (srow & 7)) << 3);      // element offset in row
    const unsigned short* aG = Xb + (long long)(bm0 + srow) * 4096 + g * 1024 + cswz8;
    const unsigned short* bG = Wq + (long long)(bn0 + srow) * 1024 + cswz8;

    // read-side swizzle: kb = ks*4 + (lane>>4), slot = kb ^ (row&7), row&7 == lane&7
    const int col0 = (((lane >> 4) ^ (lane & 7)) << 3);
    const int col1 = col0 ^ 32;

    // LDS region bases (elements): buf0 A, buf0 B, buf1 A, buf1 B
    enum { A0 = 0, B0 = 16384, A1 = 32768, B1 = 49152 };

    const int aRow = (wr * 128 + laneR) * 64;   // + 4096 for high half, + mi*1024
    const int bRow = (wc * 64 + laneR) * 64;    // + ni*1024

#define STAGE_A(base, kt, h) do { \
    async16(aG + ((long long)((h) * 128) * 4096 + (kt) * 64),      ls + (base) + (h) * 8192 + tid * 8); \
    async16(aG + ((long long)((h) * 128 + 64) * 4096 + (kt) * 64), ls + (base) + (h) * 8192 + 4096 + tid * 8); \
} while (0)
#define STAGE_B(base, kt, h) do { \
    async16(bG + ((long long)((h) * 128) * 1024 + (kt) * 64),      ls + (base) + (h) * 8192 + tid * 8); \
    async16(bG + ((long long)((h) * 128 + 64) * 1024 + (kt) * 64), ls + (base) + (h) * 8192 + 4096 + tid * 8); \
} while (0)
#define LD(off) (*(const bf16x8*)(ls + (off)))
// one MFMA acc-row (4 MFMA), SWAPPED operands: D row-dim = B's n, col-dim = A's m
#define MROW(AI, NB, FF, BB) do { \
    _Pragma("unroll") \
    for (int ni = 0; ni < 2; ++ni) { \
        acc[AI][(NB) + ni] = __builtin_amdgcn_mfma_f32_16x16x32_bf16((BB)[ni][0], (FF)[0], acc[AI][(NB) + ni], 0, 0, 0); \
        acc[AI][(NB) + ni] = __builtin_amdgcn_mfma_f32_16x16x32_bf16((BB)[ni][1], (FF)[1], acc[AI][(NB) + ni], 0, 0, 0); \
    } \
} while (0)
#define BAR() __builtin_amdgcn_s_barrier()
#define PRIO1() __builtin_amdgcn_s_setprio(1)
#define PRIO0() __builtin_amdgcn_s_setprio(0)

    f32x4 acc[8][4];
    #pragma unroll
    for (int i = 0; i < 8; ++i)
        #pragma unroll
        for (int j = 0; j < 4; ++j) acc[i][j] = (f32x4){0.f, 0.f, 0.f, 0.f};

    bf16x8 a[4][2], ah2[2][2], b[2][2], c[2][2];

    // ---- prologue: kt0 full into buf0 (8 loads), B(kt1) into buf1 (4 loads)
    STAGE_A(A0, 0, 0); STAGE_A(A0, 0, 1);
    STAGE_B(B0, 0, 0); STAGE_B(B0, 0, 1);
    STAGE_B(B1, 1, 0); STAGE_B(B1, 1, 1);
    asm volatile("s_waitcnt vmcnt(4)" ::: "memory");   // kt0 resident; B(kt1) in flight
    BAR();

    #pragma unroll 1
    for (int it = 0; it < 8; ++it) {
        const int kt1 = it * 2 + 1;
        const bool pf = (it < 7);

        // ---- P1: reads b01 + aLow (buf0); stage A_h0(kt1)->buf1; MFMA Q(0,0) ----
        #pragma unroll
        for (int ni = 0; ni < 2; ++ni) { b[ni][0] = LD(B0 + bRow + ni * 1024 + col0); b[ni][1] = LD(B0 + bRow + ni * 1024 + col1); }
        #pragma unroll
        for (int mi = 0; mi < 4; ++mi) { a[mi][0] = LD(A0 + aRow + mi * 1024 + col0); a[mi][1] = LD(A0 + aRow + mi * 1024 + col1); }
        STAGE_A(A1, kt1, 0);
        BAR(); PRIO1();
        MROW(0, 0, a[0], b); MROW(1, 0, a[1], b); MROW(2, 0, a[2], b); MROW(3, 0, a[3], b);
        PRIO0(); BAR();

        // ---- P2: reads b23 + aHigh01 (buf0); stage A_h1(kt1)->buf1; MFMA Q(0,1) ----
        #pragma unroll
        for (int ni = 0; ni < 2; ++ni) { c[ni][0] = LD(B0 + bRow + (ni + 2) * 1024 + col0); c[ni][1] = LD(B0 + bRow + (ni + 2) * 1024 + col1); }
        #pragma unroll
        for (int j = 0; j < 2; ++j) { ah2[j][0] = LD(A0 + aRow + 4096 + j * 1024 + col0); ah2[j][1] = LD(A0 + aRow + 4096 + j * 1024 + col1); }
        STAGE_A(A1, kt1, 1);
        BAR(); PRIO1();
        MROW(0, 2, a[0], c); MROW(1, 2, a[1], c); MROW(2, 2, a[2], c); MROW(3, 2, a[3], c);
        PRIO0(); BAR();

        // ---- P3: reads aHigh23 (buf0, into dead aLow regs); stage B_h0(kt+2); MFMA Q(1,0) ----
        #pragma unroll
        for (int j = 0; j < 2; ++j) { a[j][0] = LD(A0 + aRow + 4096 + (j + 2) * 1024 + col0); a[j][1] = LD(A0 + aRow + 4096 + (j + 2) * 1024 + col1); }
        if (pf) STAGE_B(B0, kt1 + 1, 0);
        BAR(); PRIO1();
        MROW(4, 0, ah2[0], b); MROW(5, 0, ah2[1], b); MROW(6, 0, a[0], b); MROW(7, 0, a[1], b);
        PRIO0(); BAR();

        // ---- P4: stage B_h1(kt+2); MFMA Q(1,1); counted vmcnt ----
        if (pf) STAGE_B(B0, kt1 + 1, 1);
        BAR(); PRIO1();
        MROW(4, 2, ah2[0], c); MROW(5, 2, ah2[1], c); MROW(6, 2, a[0], c); MROW(7, 2, a[1], c);
        PRIO0();
        if (pf) { asm volatile("s_waitcnt vmcnt(4)" ::: "memory"); }
        else    { asm volatile("s_waitcnt vmcnt(0)" ::: "memory"); }
        BAR();

        // ---- P5: reads b01 + aLow (buf1); stage A_h0(kt+2)->buf0; MFMA Q(0,0) ----
        #pragma unroll
        for (int ni = 0; ni < 2; ++ni) { b[ni][0] = LD(B1 + bRow + ni * 1024 + col0); b[ni][1] = LD(B1 + bRow + ni * 1024 + col1); }
        #pragma unroll
        for (int mi = 0; mi < 4; ++mi) { a[mi][0] = LD(A1 + aRow + mi * 1024 + col0); a[mi][1] = LD(A1 + aRow + mi * 1024 + col1); }
        if (pf) STAGE_A(A0, kt1 + 1, 0);
        BAR(); PRIO1();
        MROW(0, 0, a[0], b); MROW(1, 0, a[1], b); MROW(2, 0, a[2], b); MROW(3, 0, a[3], b);
        PRIO0(); BAR();

        // ---- P6: reads b23 + aHigh01 (buf1); stage A_h1(kt+2)->buf0; MFMA Q(0,1) ----
        #pragma unroll
        for (int ni = 0; ni < 2; ++ni) { c[ni][0] = LD(B1 + bRow + (ni + 2) * 1024 + col0); c[ni][1] = LD(B1 + bRow + (ni + 2) * 1024 + col1); }
        #pragma unroll
        for (int j = 0; j < 2; ++j) { ah2[j][0] = LD(A1 + aRow + 4096 + j * 1024 + col0); ah2[j][1] = LD(A1 + aRow + 4096 + j * 1024 + col1); }
        if (pf) STAGE_A(A0, kt1 + 1, 1);
        BAR(); PRIO1();
        MROW(0, 2, a[0], c); MROW(1, 2, a[1], c); MROW(2, 2, a[2], c); MROW(3, 2, a[3], c);
        PRIO0(); BAR();

        // ---- P7: reads aHigh23 (buf1); stage B_h0(kt1+2)->buf1; MFMA Q(1,0) ----
        #pragma unroll
        for (int j = 0; j < 2; ++j) { a[j][0] = LD(A1 + aRow + 4096 + (j + 2) * 1024 + col0); a[j][1] = LD(A1 + aRow + 4096 + (j + 2) * 1024 + col1); }
        if (pf) STAGE_B(B1, kt1 + 2, 0);
        BAR(); PRIO1();
        MROW(4, 0, ah2[0], b); MROW(5, 0, ah2[1], b); MROW(6, 0, a[0], b); MROW(7, 0, a[1], b);
        PRIO0(); BAR();

        // ---- P8: stage B_h1(kt1+2); MFMA Q(1,1); counted vmcnt ----
        if (pf) STAGE_B(B1, kt1 + 2, 1);
        BAR(); PRIO1();
        MROW(4, 2, ah2[0], c); MROW(5, 2, ah2[1], c); MROW(6, 2, a[0], c); MROW(7, 2, a[1], c);
        PRIO0();
        if (pf) { asm volatile("s_waitcnt vmcnt(4)" ::: "memory"); }
        BAR();
    }

    // ---- epilogue: direct f32x4 stores from accumulators ----
    // Swapped-operand D layout: m = lane&15 (fixed per lane), n = (lane>>4)*4 + r.
    // acc[mi][ni] = Out[bm0+wr*128+mi*16+laneR][bn0+wc*64+ni*16+(lane>>4)*4 .. +3]
    // Lanes {l,l+16,l+32,l+48} tile one row's 64 floats (256 B) contiguously.
    {
        const int nq = (lane >> 4) * 4;
        #pragma unroll
        for (int mi = 0; mi < 8; ++mi) {
            const long long rg = (long long)(bm0 + wr * 128 + mi * 16 + laneR);
            float* orow = Out + rg * 4096 + bn0 + wc * 64 + nq;
            #pragma unroll
            for (int ni = 0; ni < 4; ++ni)
                *(f32x4*)&orow[ni * 16] = acc[mi][ni];
        }
    }
#undef STAGE_A
#undef STAGE_B
#undef LD
#undef MROW
#undef BAR
#undef PRIO1
#undef PRIO0
}

// ---------- launcher ----------
extern "C" void kernel_launch(void* const* d_in, const int* in_sizes, int n_in,
                              void* d_out, int out_size, void* d_ws, size_t ws_size,
                              hipStream_t stream) {
    const float* x = (const float*)d_in[0];     // (2,4096,4096) fp32
    const float* w = (const float*)d_in[1];     // (4096,1024) fp32
    float* out = (float*)d_out;                 // (2,4096,4096) fp32

    unsigned short* xb = (unsigned short*)d_ws;                   // 8192*4096 bf16 = 64 MiB
    unsigned short* wq = xb + (size_t)8192 * 4096;                // 4096*1024 bf16 = 8 MiB

    quant_kernel<<<4096 * 1024 / 256, 256, 0, stream>>>(w, wq);
    norm_kernel<<<8192, 256, 0, stream>>>(x, xb);
    gemm_kernel<<<512, 512, 0, stream>>>(xb, wq, out);
}